// Round 1
// baseline (571.506 us; speedup 1.0000x reference)
//
#include <hip/hip_runtime.h>

// LittleBitITQSpecLinear: y = sum_b ((x*v2_b) @ sign(V_b)^T * (v1_b*u2_b)) @ sign(U_b)^T * u1_b + bias
// Folded: W1_b[s,k] = sign(V_b[s,k])*v2_b[k];  W2_b[o,s] = sign(U_b[o,s])*v1_b[s]*u2_b[s]*u1_b[o]
// => H = Xbf16 @ W1cat^T  (8192x2048, K=4096);  Y = H @ W2cat^T + bias (8192x4096, K=2048)

typedef __bf16 bf16x8 __attribute__((ext_vector_type(8)));
typedef float floatx4 __attribute__((ext_vector_type(4)));

__device__ __forceinline__ unsigned short f2bf_rne(float f) {
    union { float f; unsigned u; } v; v.f = f;
    unsigned r = v.u + 0x7FFFu + ((v.u >> 16) & 1u);
    return (unsigned short)(r >> 16);
}

__device__ __forceinline__ float sgnf(float w) {
    return (float)((w > 0.f) - (w < 0.f));
}

__device__ __forceinline__ void async_copy16(const void* g, void* l) {
    __builtin_amdgcn_global_load_lds(
        (const __attribute__((address_space(1))) void*)g,
        (__attribute__((address_space(3))) void*)l, 16, 0, 0);
}

// ---------------- prep kernels ----------------

__global__ void cast_x_kernel(const float* __restrict__ x,
                              unsigned short* __restrict__ xb, int n4) {
    int i = blockIdx.x * blockDim.x + threadIdx.x;
    if (i >= n4) return;
    float4 v = ((const float4*)x)[i];
    ushort4 o;
    o.x = f2bf_rne(v.x); o.y = f2bf_rne(v.y);
    o.z = f2bf_rne(v.z); o.w = f2bf_rne(v.w);
    ((ushort4*)xb)[i] = o;
}

// W1cat[s_cat][k], s_cat in [0,2048), k in [0,4096)
__global__ void prep_w1_kernel(const float* __restrict__ V, const float* __restrict__ V_R,
                               const float* __restrict__ v2, const float* __restrict__ v2_R,
                               unsigned short* __restrict__ W1) {
    int i = blockIdx.x * blockDim.x + threadIdx.x;  // 4 elems each
    int idx = i << 2;
    int scat = idx >> 12;
    int k = idx & 4095;
    const float* Vp; const float* sp;
    if (scat < 1024) { Vp = V + ((size_t)scat << 12); sp = v2; }
    else             { Vp = V_R + ((size_t)(scat - 1024) << 12); sp = v2_R; }
    float4 w = *(const float4*)(Vp + k);
    float4 s = *(const float4*)(sp + k);
    ushort4 o;
    o.x = f2bf_rne(sgnf(w.x) * s.x);
    o.y = f2bf_rne(sgnf(w.y) * s.y);
    o.z = f2bf_rne(sgnf(w.z) * s.z);
    o.w = f2bf_rne(sgnf(w.w) * s.w);
    ((ushort4*)W1)[i] = o;
}

// W2cat[o][s_cat], o in [0,4096), s_cat in [0,2048)
__global__ void prep_w2_kernel(const float* __restrict__ U, const float* __restrict__ U_R,
                               const float* __restrict__ v1, const float* __restrict__ v1_R,
                               const float* __restrict__ u2, const float* __restrict__ u2_R,
                               const float* __restrict__ u1, const float* __restrict__ u1_R,
                               unsigned short* __restrict__ W2) {
    int i = blockIdx.x * blockDim.x + threadIdx.x;  // 4 elems each
    int idx = i << 2;
    int o = idx >> 11;
    int scat = idx & 2047;
    int branch = scat >> 10;
    int s = scat & 1023;
    const float* Up  = branch ? U_R  : U;
    const float* v1p = branch ? v1_R : v1;
    const float* u2p = branch ? u2_R : u2;
    float u1v = (branch ? u1_R : u1)[o];
    float4 w = *(const float4*)(Up + ((size_t)o << 10) + s);
    float4 a = *(const float4*)(v1p + s);
    float4 b = *(const float4*)(u2p + s);
    ushort4 out;
    out.x = f2bf_rne(sgnf(w.x) * a.x * b.x * u1v);
    out.y = f2bf_rne(sgnf(w.y) * a.y * b.y * u1v);
    out.z = f2bf_rne(sgnf(w.z) * a.z * b.z * u1v);
    out.w = f2bf_rne(sgnf(w.w) * a.w * b.w * u1v);
    ((ushort4*)W2)[i] = out;
}

// ---------------- GEMM: C[M,N] = A[M,K] @ B[N,K]^T ----------------
// m97 recipe: 128x128 block tile, 4 waves (each 64x64 via 4x4 MFMA 16x16x32),
// BK=64, global_load_lds width-16 staging.

template <bool OUT_BF16, bool ADD_BIAS>
__global__ void gemm_bt(const unsigned short* __restrict__ A,
                        const unsigned short* __restrict__ B,
                        void* __restrict__ Cv,
                        const float* __restrict__ bias,
                        int M, int N, int K) {
    __shared__ __align__(16) unsigned short As[128 * 64];
    __shared__ __align__(16) unsigned short Bs[128 * 64];

    const int tid = threadIdx.x;
    const int wave = tid >> 6;
    const int lane = tid & 63;
    const int m0 = blockIdx.x * 128;
    const int n0 = blockIdx.y * 128;

    // staging: per wave-instruction, 64 lanes x 16B = 8 rows of 64 bf16
    const int lrow = lane >> 3;          // 0..7
    const int lcol = (lane & 7) << 3;    // 0..56, step 8

    // fragment indexing
    const int wm = (wave >> 1) << 6;     // 0 or 64
    const int wn = (wave & 1) << 6;      // 0 or 64
    const int fm = lane & 15;
    const int fk = (lane >> 4) << 3;

    floatx4 acc[4][4];
#pragma unroll
    for (int i = 0; i < 4; ++i)
#pragma unroll
        for (int j = 0; j < 4; ++j)
#pragma unroll
            for (int r = 0; r < 4; ++r) acc[i][j][r] = 0.f;

    const size_t Ks = (size_t)K;
    for (int k0 = 0; k0 < K; k0 += 64) {
#pragma unroll
        for (int i = 0; i < 4; ++i) {
            const int row = wave * 32 + i * 8;   // wave-uniform
            const unsigned short* gA = A + (size_t)(m0 + row + lrow) * Ks + (k0 + lcol);
            const unsigned short* gB = B + (size_t)(n0 + row + lrow) * Ks + (k0 + lcol);
            async_copy16(gA, &As[row * 64]);
            async_copy16(gB, &Bs[row * 64]);
        }
        __syncthreads();
#pragma unroll
        for (int ks = 0; ks < 64; ks += 32) {
            bf16x8 af[4], bfr[4];
#pragma unroll
            for (int i = 0; i < 4; ++i)
                af[i] = *(const bf16x8*)&As[(wm + i * 16 + fm) * 64 + ks + fk];
#pragma unroll
            for (int i = 0; i < 4; ++i)
                bfr[i] = *(const bf16x8*)&Bs[(wn + i * 16 + fm) * 64 + ks + fk];
#pragma unroll
            for (int mi = 0; mi < 4; ++mi)
#pragma unroll
                for (int ni = 0; ni < 4; ++ni)
                    acc[mi][ni] = __builtin_amdgcn_mfma_f32_16x16x32_bf16(
                        af[mi], bfr[ni], acc[mi][ni], 0, 0, 0);
        }
        __syncthreads();
    }

    // epilogue: C/D layout col=lane&15, row=(lane>>4)*4+reg  [m89-verified]
    const int rq = (lane >> 4) << 2;
    const int col = lane & 15;
#pragma unroll
    for (int mi = 0; mi < 4; ++mi) {
#pragma unroll
        for (int r = 0; r < 4; ++r) {
            const int gm = m0 + wm + mi * 16 + rq + r;
            const size_t base = (size_t)gm * (size_t)N;
#pragma unroll
            for (int ni = 0; ni < 4; ++ni) {
                const int gn = n0 + wn + ni * 16 + col;
                float v = acc[mi][ni][r];
                if (ADD_BIAS) v += bias[gn];
                if (OUT_BF16)
                    ((unsigned short*)Cv)[base + gn] = f2bf_rne(v);
                else
                    ((float*)Cv)[base + gn] = v;
            }
        }
    }
}

// ---------------- launch ----------------

extern "C" void kernel_launch(void* const* d_in, const int* in_sizes, int n_in,
                              void* d_out, int out_size, void* d_ws, size_t ws_size,
                              hipStream_t stream) {
    const float* x    = (const float*)d_in[0];
    const float* V    = (const float*)d_in[1];
    const float* U    = (const float*)d_in[2];
    const float* v2   = (const float*)d_in[3];
    const float* v1   = (const float*)d_in[4];
    const float* u2   = (const float*)d_in[5];
    const float* u1   = (const float*)d_in[6];
    const float* V_R  = (const float*)d_in[7];
    const float* U_R  = (const float*)d_in[8];
    const float* v2_R = (const float*)d_in[9];
    const float* v1_R = (const float*)d_in[10];
    const float* u2_R = (const float*)d_in[11];
    const float* u1_R = (const float*)d_in[12];
    const float* bias = (const float*)d_in[13];
    float* out = (float*)d_out;

    char* ws = (char*)d_ws;
    unsigned short* Xb = (unsigned short*)ws;                                   // 8192*4096*2 = 64 MiB
    unsigned short* W1 = (unsigned short*)(ws + (size_t)67108864);              // 2048*4096*2 = 16 MiB
    unsigned short* W2 = (unsigned short*)(ws + (size_t)67108864 + 16777216);   // 4096*2048*2 = 16 MiB
    unsigned short* H  = (unsigned short*)(ws + (size_t)67108864 + 33554432);   // 8192*2048*2 = 32 MiB

    // x: 8192*4096 = 33554432 floats -> /4 = 8388608 threads
    cast_x_kernel<<<32768, 256, 0, stream>>>(x, Xb, 8388608);
    // W1: 2048*4096/4 = 2097152 threads
    prep_w1_kernel<<<8192, 256, 0, stream>>>(V, V_R, v2, v2_R, W1);
    // W2: 4096*2048/4 = 2097152 threads
    prep_w2_kernel<<<8192, 256, 0, stream>>>(U, U_R, v1, v1_R, u2, u2_R, u1, u1_R, W2);

    // GEMM1: H[8192,2048] = Xb @ W1^T, K=4096
    gemm_bt<true, false><<<dim3(64, 16), 256, 0, stream>>>(Xb, W1, (void*)H, nullptr, 8192, 2048, 4096);
    // GEMM2: Y[8192,4096] = H @ W2^T + bias, K=2048
    gemm_bt<false, true><<<dim3(64, 32), 256, 0, stream>>>(H, W2, (void*)out, bias, 8192, 4096, 2048);
}

// Round 2
// 546.699 us; speedup vs baseline: 1.0454x; 1.0454x over previous
//
#include <hip/hip_runtime.h>

// LittleBitITQSpecLinear: y = sum_b ((x*v2_b) @ sign(V_b)^T * (v1_b*u2_b)) @ sign(U_b)^T * u1_b + bias
// Folded: W1_b[s,k] = sign(V_b[s,k])*v2_b[k];  W2_b[o,s] = sign(U_b[o,s])*v1_b[s]*u2_b[s]*u1_b[o]
// => H = Xbf16 @ W1cat^T  (8192x2048, K=4096);  Y = H @ W2cat^T + bias (8192x4096, K=2048)
//
// R2: XOR-swizzled LDS layout (fetch-side swizzle, since global_load_lds pins
// dest = base + lane*16). LDS[r][c] holds global chunk c ^ (r&7); fragment
// reads access chunk cg ^ (r&7) -> 2 lanes per 4-bank group (free, m136)
// instead of 16-way conflicts. Also fused the two weight-prep kernels.

typedef __bf16 bf16x8 __attribute__((ext_vector_type(8)));
typedef float floatx4 __attribute__((ext_vector_type(4)));

__device__ __forceinline__ unsigned short f2bf_rne(float f) {
    union { float f; unsigned u; } v; v.f = f;
    unsigned r = v.u + 0x7FFFu + ((v.u >> 16) & 1u);
    return (unsigned short)(r >> 16);
}

__device__ __forceinline__ float sgnf(float w) {
    return (float)((w > 0.f) - (w < 0.f));
}

__device__ __forceinline__ void async_copy16(const void* g, void* l) {
    __builtin_amdgcn_global_load_lds(
        (const __attribute__((address_space(1))) void*)g,
        (__attribute__((address_space(3))) void*)l, 16, 0, 0);
}

// ---------------- prep kernels ----------------

__global__ void cast_x_kernel(const float* __restrict__ x,
                              unsigned short* __restrict__ xb, int n4) {
    int i = blockIdx.x * blockDim.x + threadIdx.x;
    if (i >= n4) return;
    float4 v = ((const float4*)x)[i];
    ushort4 o;
    o.x = f2bf_rne(v.x); o.y = f2bf_rne(v.y);
    o.z = f2bf_rne(v.z); o.w = f2bf_rne(v.w);
    ((ushort4*)xb)[i] = o;
}

// Fused weight prep. Blocks [0,8192): W1cat[s_cat][k] (2048x4096).
// Blocks [8192,16384): W2cat[o][s_cat] (4096x2048).
__global__ void prep_w_kernel(const float* __restrict__ V, const float* __restrict__ V_R,
                              const float* __restrict__ v2, const float* __restrict__ v2_R,
                              const float* __restrict__ U, const float* __restrict__ U_R,
                              const float* __restrict__ v1, const float* __restrict__ v1_R,
                              const float* __restrict__ u2, const float* __restrict__ u2_R,
                              const float* __restrict__ u1, const float* __restrict__ u1_R,
                              unsigned short* __restrict__ W1,
                              unsigned short* __restrict__ W2) {
    int bid = blockIdx.x;
    if (bid < 8192) {
        int i = bid * blockDim.x + threadIdx.x;  // 4 elems each
        int idx = i << 2;
        int scat = idx >> 12;
        int k = idx & 4095;
        const float* Vp; const float* sp;
        if (scat < 1024) { Vp = V + ((size_t)scat << 12); sp = v2; }
        else             { Vp = V_R + ((size_t)(scat - 1024) << 12); sp = v2_R; }
        float4 w = *(const float4*)(Vp + k);
        float4 s = *(const float4*)(sp + k);
        ushort4 o;
        o.x = f2bf_rne(sgnf(w.x) * s.x);
        o.y = f2bf_rne(sgnf(w.y) * s.y);
        o.z = f2bf_rne(sgnf(w.z) * s.z);
        o.w = f2bf_rne(sgnf(w.w) * s.w);
        ((ushort4*)W1)[i] = o;
    } else {
        int i = (bid - 8192) * blockDim.x + threadIdx.x;  // 4 elems each
        int idx = i << 2;
        int o = idx >> 11;
        int scat = idx & 2047;
        int branch = scat >> 10;
        int s = scat & 1023;
        const float* Up  = branch ? U_R  : U;
        const float* v1p = branch ? v1_R : v1;
        const float* u2p = branch ? u2_R : u2;
        float u1v = (branch ? u1_R : u1)[o];
        float4 w = *(const float4*)(Up + ((size_t)o << 10) + s);
        float4 a = *(const float4*)(v1p + s);
        float4 b = *(const float4*)(u2p + s);
        ushort4 out;
        out.x = f2bf_rne(sgnf(w.x) * a.x * b.x * u1v);
        out.y = f2bf_rne(sgnf(w.y) * a.y * b.y * u1v);
        out.z = f2bf_rne(sgnf(w.z) * a.z * b.z * u1v);
        out.w = f2bf_rne(sgnf(w.w) * a.w * b.w * u1v);
        ((ushort4*)W2)[i] = out;
    }
}

// ---------------- GEMM: C[M,N] = A[M,K] @ B[N,K]^T ----------------
// m97 recipe: 128x128 block tile, 4 waves (each 64x64 via 4x4 MFMA 16x16x32),
// BK=64, global_load_lds width-16 staging, XOR-swizzled LDS chunks.

template <bool OUT_BF16, bool ADD_BIAS>
__global__ void gemm_bt(const unsigned short* __restrict__ A,
                        const unsigned short* __restrict__ B,
                        void* __restrict__ Cv,
                        const float* __restrict__ bias,
                        int M, int N, int K) {
    __shared__ __align__(16) unsigned short As[128 * 64];
    __shared__ __align__(16) unsigned short Bs[128 * 64];

    const int tid = threadIdx.x;
    const int wave = tid >> 6;
    const int lane = tid & 63;
    const int m0 = blockIdx.x * 128;
    const int n0 = blockIdx.y * 128;

    // staging: per wave-instruction, 64 lanes x 16B = 8 rows of 64 bf16.
    // Fetch-side XOR swizzle: lane (lrow, chunk) fetches global chunk
    // chunk ^ lrow, so LDS[r][c] = global[r][c ^ (r&7)].
    const int lrow = lane >> 3;                         // 0..7
    const int lcol = (((lane & 7) ^ lrow)) << 3;        // swizzled chunk * 8 elems

    // fragment indexing
    const int wm = (wave >> 1) << 6;     // 0 or 64
    const int wn = (wave & 1) << 6;      // 0 or 64
    const int fm = lane & 15;
    const int rk = lane & 7;             // read xor key = (row & 7)
    const int cgl = lane >> 4;           // chunk bits 0-1 from lane

    floatx4 acc[4][4];
#pragma unroll
    for (int i = 0; i < 4; ++i)
#pragma unroll
        for (int j = 0; j < 4; ++j)
#pragma unroll
            for (int r = 0; r < 4; ++r) acc[i][j][r] = 0.f;

    const size_t Ks = (size_t)K;
    for (int k0 = 0; k0 < K; k0 += 64) {
#pragma unroll
        for (int i = 0; i < 4; ++i) {
            const int row = wave * 32 + i * 8;   // wave-uniform
            const unsigned short* gA = A + (size_t)(m0 + row + lrow) * Ks + (k0 + lcol);
            const unsigned short* gB = B + (size_t)(n0 + row + lrow) * Ks + (k0 + lcol);
            async_copy16(gA, &As[row * 64]);
            async_copy16(gB, &Bs[row * 64]);
        }
        __syncthreads();
#pragma unroll
        for (int ks = 0; ks < 64; ks += 32) {
            const int cg = (ks >> 3) | cgl;              // global chunk 0..7
            const int roff = (cg ^ rk) << 3;             // swizzled elem offset
            bf16x8 af[4], bfr[4];
#pragma unroll
            for (int i = 0; i < 4; ++i)
                af[i] = *(const bf16x8*)&As[(wm + i * 16 + fm) * 64 + roff];
#pragma unroll
            for (int i = 0; i < 4; ++i)
                bfr[i] = *(const bf16x8*)&Bs[(wn + i * 16 + fm) * 64 + roff];
#pragma unroll
            for (int mi = 0; mi < 4; ++mi)
#pragma unroll
                for (int ni = 0; ni < 4; ++ni)
                    acc[mi][ni] = __builtin_amdgcn_mfma_f32_16x16x32_bf16(
                        af[mi], bfr[ni], acc[mi][ni], 0, 0, 0);
        }
        __syncthreads();
    }

    // epilogue: C/D layout col=lane&15, row=(lane>>4)*4+reg  [m89-verified]
    const int rq = (lane >> 4) << 2;
    const int col = lane & 15;
#pragma unroll
    for (int mi = 0; mi < 4; ++mi) {
#pragma unroll
        for (int r = 0; r < 4; ++r) {
            const int gm = m0 + wm + mi * 16 + rq + r;
            const size_t base = (size_t)gm * (size_t)N;
#pragma unroll
            for (int ni = 0; ni < 4; ++ni) {
                const int gn = n0 + wn + ni * 16 + col;
                float v = acc[mi][ni][r];
                if (ADD_BIAS) v += bias[gn];
                if (OUT_BF16)
                    ((unsigned short*)Cv)[base + gn] = f2bf_rne(v);
                else
                    ((float*)Cv)[base + gn] = v;
            }
        }
    }
}

// ---------------- launch ----------------

extern "C" void kernel_launch(void* const* d_in, const int* in_sizes, int n_in,
                              void* d_out, int out_size, void* d_ws, size_t ws_size,
                              hipStream_t stream) {
    const float* x    = (const float*)d_in[0];
    const float* V    = (const float*)d_in[1];
    const float* U    = (const float*)d_in[2];
    const float* v2   = (const float*)d_in[3];
    const float* v1   = (const float*)d_in[4];
    const float* u2   = (const float*)d_in[5];
    const float* u1   = (const float*)d_in[6];
    const float* V_R  = (const float*)d_in[7];
    const float* U_R  = (const float*)d_in[8];
    const float* v2_R = (const float*)d_in[9];
    const float* v1_R = (const float*)d_in[10];
    const float* u2_R = (const float*)d_in[11];
    const float* u1_R = (const float*)d_in[12];
    const float* bias = (const float*)d_in[13];
    float* out = (float*)d_out;

    char* ws = (char*)d_ws;
    unsigned short* Xb = (unsigned short*)ws;                                   // 8192*4096*2 = 64 MiB
    unsigned short* W1 = (unsigned short*)(ws + (size_t)67108864);              // 2048*4096*2 = 16 MiB
    unsigned short* W2 = (unsigned short*)(ws + (size_t)67108864 + 16777216);   // 4096*2048*2 = 16 MiB
    unsigned short* H  = (unsigned short*)(ws + (size_t)67108864 + 33554432);   // 8192*2048*2 = 32 MiB

    // x: 8192*4096 = 33554432 floats -> /4 = 8388608 threads
    cast_x_kernel<<<32768, 256, 0, stream>>>(x, Xb, 8388608);
    // fused weight prep: 8192 blocks W1 + 8192 blocks W2
    prep_w_kernel<<<16384, 256, 0, stream>>>(V, V_R, v2, v2_R,
                                             U, U_R, v1, v1_R, u2, u2_R, u1, u1_R,
                                             W1, W2);

    // GEMM1: H[8192,2048] = Xb @ W1^T, K=4096
    gemm_bt<true, false><<<dim3(64, 16), 256, 0, stream>>>(Xb, W1, (void*)H, nullptr, 8192, 2048, 4096);
    // GEMM2: Y[8192,4096] = H @ W2^T + bias, K=2048
    gemm_bt<false, true><<<dim3(64, 32), 256, 0, stream>>>(H, W2, (void*)out, bias, 8192, 4096, 2048);
}